// Round 2
// baseline (23550.429 us; speedup 1.0000x reference)
//
#include <hip/hip_runtime.h>

// BiLSTM: B=2048, T=200, D=U=128, 2 layers, bidirectional, merge='ave'.
// Persistent per-(batch-tile, direction) blocks; both layers fused per
// timestep; h/c state in LDS/regs; weights streamed from L1/L2.
// R1: 1024 thr/block (16 waves -> 4/SIMD) + unroll-4 load pipeline.

#define NB   2048
#define NTT  200
#define ND   128
#define NG   512   // 4*UNITS
#define MT   16    // batch rows per block
#define NTHR 1024  // 16 waves
#define AS   132   // LDS stride for A-tiles (x/h), padded
#define ZS   516   // LDS stride for z buffer, padded

__device__ __forceinline__ float rcp_f(float x){ return __builtin_amdgcn_rcpf(x); }
__device__ __forceinline__ float sigm(float x){ return rcp_f(1.f + __expf(-x)); }
// tanh(x) = 1 - 2/(e^{2x}+1): graceful at +/-inf (no NaN)
__device__ __forceinline__ float tanh_f(float x){ return 1.f - 2.f*rcp_f(__expf(2.f*x) + 1.f); }

__device__ __forceinline__ void set4(float (&a)[4], const float4 v){ a[0]=v.x; a[1]=v.y; a[2]=v.z; a[3]=v.w; }
__device__ __forceinline__ void fma4(float (&a)[4], float s, const float4 b){
  a[0] = __builtin_fmaf(s, b.x, a[0]);
  a[1] = __builtin_fmaf(s, b.y, a[1]);
  a[2] = __builtin_fmaf(s, b.z, a[2]);
  a[3] = __builtin_fmaf(s, b.w, a[3]);
}

// One row per thread: acc[2][4] covers cols c0..c0+3 and c0+256..c0+259.
__device__ __forceinline__ void gemm_acc1(float (&acc)[2][4],
    const float* A0, const float* __restrict__ Bm, int c0)
{
  #pragma unroll 4
  for (int k4 = 0; k4 < ND; k4 += 4){
    float4 a0 = *(const float4*)(A0 + k4);           // LDS broadcast (same addr per wave)
    const float* br = Bm + (size_t)k4 * NG + c0;
    #pragma unroll
    for (int kk = 0; kk < 4; ++kk){
      float4 bA = *(const float4*)(br + kk*NG);
      float4 bB = *(const float4*)(br + kk*NG + 256);
      float s0 = (&a0.x)[kk];
      fma4(acc[0], s0, bA); fma4(acc[1], s0, bB);
    }
  }
}

__device__ __forceinline__ void cell_update(const float* zrow, float (&c)[4], float (&h)[4])
{
  float4 zi4 = *(const float4*)(zrow);
  float4 zf4 = *(const float4*)(zrow + ND);
  float4 zg4 = *(const float4*)(zrow + 2*ND);
  float4 zo4 = *(const float4*)(zrow + 3*ND);
  const float* zi = &zi4.x; const float* zf = &zf4.x;
  const float* zg = &zg4.x; const float* zo = &zo4.x;
  #pragma unroll
  for (int q = 0; q < 4; ++q){
    float iv = sigm(zi[q]);
    float fv = sigm(zf[q]);
    float gv = tanh_f(zg[q]);
    float ov = sigm(zo[q]);
    float cv = __builtin_fmaf(fv, c[q], iv*gv);
    c[q] = cv;
    h[q] = ov * tanh_f(cv);
  }
}

__global__ void __launch_bounds__(NTHR)
bilstm_fused(const float* __restrict__ x,
             const float* __restrict__ Wf, const float* __restrict__ Uf, const float* __restrict__ bf,
             const float* __restrict__ Wb, const float* __restrict__ Ub, const float* __restrict__ bb,
             float* __restrict__ dstFw, float* __restrict__ dstBw, int atomicOut)
{
  __shared__ float xa [MT*AS];   // layer-0 input tile, [r][k]
  __shared__ float h0a[MT*AS];   // layer-0 h state,    [r][k]
  __shared__ float h1a[MT*AS];   // layer-1 h state,    [r][k]
  __shared__ float zb [MT*ZS];   // gate pre-activations, [r][512]

  const int tid = threadIdx.x;
  const int dir = blockIdx.y;          // 0 = fw, 1 = bw
  const int b0  = blockIdx.x * MT;

  const float* W0 = dir ? Wb : Wf;
  const float* U0 = dir ? Ub : Uf;
  const float* B0 = dir ? bb : bf;
  const float* W1 = W0 + ND*NG;
  const float* U1 = U0 + ND*NG;
  const float* B1 = B0 + NG;
  float* dst = dir ? dstBw : dstFw;

  const int lane = tid & 63;
  const int r0   = tid >> 6;           // wave id 0..15 -> one A-row per wave
  const int c0   = lane * 4;           // cols c0..c0+3 and c0+256..c0+259

  const float4 bv00 = *(const float4*)(B0 + c0);
  const float4 bv01 = *(const float4*)(B0 + 256 + c0);
  const float4 bv10 = *(const float4*)(B1 + c0);
  const float4 bv11 = *(const float4*)(B1 + 256 + c0);

  // elementwise/staging mapping (first 512 threads): (er, ej..ej+3)
  const int er = (tid & 511) >> 5;     // 0..15
  const int ej = (tid & 31) * 4;       // 0..124

  float c0r[4] = {0.f,0.f,0.f,0.f};
  float c1r[4] = {0.f,0.f,0.f,0.f};

  for (int i = tid; i < MT*AS; i += NTHR){ h0a[i] = 0.f; h1a[i] = 0.f; }
  __syncthreads();

  for (int t = 0; t < NTT; ++t){
    const int te = dir ? (NTT-1-t) : t;

    // stage x tile (512 threads, one float4 each, coalesced per row)
    if (tid < 512)
      *(float4*)(xa + er*AS + ej) =
          *(const float4*)(x + ((size_t)(b0+er)*NTT + te)*ND + ej);
    __syncthreads();                       // xa ready

    float acc[2][4];

    // ---------- layer 0: z = b0 + x_t@W0 + h0@U0
    set4(acc[0], bv00); set4(acc[1], bv01);
    gemm_acc1(acc, xa  + r0*AS, W0, c0);
    gemm_acc1(acc, h0a + r0*AS, U0, c0);
    *(float4*)(zb + (size_t)r0*ZS + c0)       = make_float4(acc[0][0],acc[0][1],acc[0][2],acc[0][3]);
    *(float4*)(zb + (size_t)r0*ZS + c0 + 256) = make_float4(acc[1][0],acc[1][1],acc[1][2],acc[1][3]);
    __syncthreads();                       // zb ready; xa free

    if (tid < 512){
      float h[4];
      cell_update(zb + (size_t)er*ZS + ej, c0r, h);
      *(float4*)(h0a + er*AS + ej) = make_float4(h[0],h[1],h[2],h[3]);
    }
    __syncthreads();                       // h0a ready

    // ---------- layer 1: z = b1 + h0@W1 + h1@U1
    set4(acc[0], bv10); set4(acc[1], bv11);
    gemm_acc1(acc, h0a + r0*AS, W1, c0);
    gemm_acc1(acc, h1a + r0*AS, U1, c0);
    *(float4*)(zb + (size_t)r0*ZS + c0)       = make_float4(acc[0][0],acc[0][1],acc[0][2],acc[0][3]);
    *(float4*)(zb + (size_t)r0*ZS + c0 + 256) = make_float4(acc[1][0],acc[1][1],acc[1][2],acc[1][3]);
    __syncthreads();                       // zb ready; all h1a reads done

    if (tid < 512){
      float h[4];
      cell_update(zb + (size_t)er*ZS + ej, c1r, h);
      *(float4*)(h1a + er*AS + ej) = make_float4(h[0],h[1],h[2],h[3]);
      float* gp = dst + ((size_t)(b0+er)*NTT + te)*ND + ej;
      if (atomicOut){
        atomicAdd(gp+0, 0.5f*h[0]); atomicAdd(gp+1, 0.5f*h[1]);
        atomicAdd(gp+2, 0.5f*h[2]); atomicAdd(gp+3, 0.5f*h[3]);
      } else {
        *(float4*)gp = make_float4(0.5f*h[0],0.5f*h[1],0.5f*h[2],0.5f*h[3]);
      }
    }
    // no trailing barrier: next-iter barriers order h1a/zb reuse
  }
}

__global__ void __launch_bounds__(256)
merge_add(float* __restrict__ out, const float* __restrict__ ws, int n4)
{
  int i = blockIdx.x*blockDim.x + threadIdx.x;
  const int stride = gridDim.x*blockDim.x;
  for (; i < n4; i += stride){
    float4 a = ((const float4*)out)[i];
    float4 b = ((const float4*)ws)[i];
    a.x += b.x; a.y += b.y; a.z += b.z; a.w += b.w;
    ((float4*)out)[i] = a;
  }
}

extern "C" void kernel_launch(void* const* d_in, const int* in_sizes, int n_in,
                              void* d_out, int out_size, void* d_ws, size_t ws_size,
                              hipStream_t stream)
{
  const float* x  = (const float*)d_in[0];
  const float* Wf = (const float*)d_in[1];
  const float* Uf = (const float*)d_in[2];
  const float* bf = (const float*)d_in[3];
  const float* Wb = (const float*)d_in[4];
  const float* Ub = (const float*)d_in[5];
  const float* bb = (const float*)d_in[6];
  float* out = (float*)d_out;

  const size_t need = (size_t)out_size * sizeof(float);
  dim3 grid(NB/MT, 2), blk(NTHR);

  if (ws_size >= need){
    // fw writes 0.5*h1f to out, bw writes 0.5*h1b to ws, then merge-add.
    float* ws = (float*)d_ws;
    bilstm_fused<<<grid, blk, 0, stream>>>(x,Wf,Uf,bf,Wb,Ub,bb,out,ws,0);
    merge_add<<<2048, 256, 0, stream>>>(out, ws, out_size/4);
  } else {
    // fallback: zero out, both directions atomically accumulate 0.5*h.
    hipMemsetAsync(out, 0, need, stream);
    bilstm_fused<<<grid, blk, 0, stream>>>(x,Wf,Uf,bf,Wb,Ub,bb,out,out,1);
  }
}

// Round 4
// 7146.883 us; speedup vs baseline: 3.2952x; 3.2952x over previous
//
#include <hip/hip_runtime.h>

// BiLSTM: B=2048, T=200, D=U=128, 2 layers, bidirectional, merge='ave'.
// R3: R2 structure + hi/lo-split WEIGHTS (3-term MFMA: ah*wh + al*wh + ah*wl)
// to remove bf16 weight-quantization error (R2 failed absmax by 1.16x).
//  - weights repacked once/launch to fragment-packed bf16 hi+lo in d_ws (2MB)
//  - wave w owns col-tiles {w,w+8,w+16,w+24} = gates i,f,g,o of units
//    16w..16w+15 -> cell update fully in-lane, c-state in VGPRs.
//  - h exchanged via fragment-packed LDS (hi+lo), double-buffered.
//  - out = memset(0) + atomicAdd 0.5*h from both dirs (commutative -> det.)

#define NB   2048
#define NTT  200
#define ND   128
#define NTHR 512   // 8 waves
#define NFRAG 65536  // frags per precision level (2 dir * 4 m * 32 CT * 4 ks * 64 lanes)

typedef short bf16x8 __attribute__((ext_vector_type(8)));
typedef float f32x4  __attribute__((ext_vector_type(4)));

__device__ __forceinline__ unsigned short f2bf(float f){
  unsigned u = __builtin_bit_cast(unsigned, f);
  u += 0x7fff + ((u >> 16) & 1);            // RNE
  return (unsigned short)(u >> 16);
}
__device__ __forceinline__ float bf2f(unsigned short h){
  unsigned u = ((unsigned)h) << 16;
  return __builtin_bit_cast(float, u);
}
__device__ __forceinline__ float rcp_f(float x){ return __builtin_amdgcn_rcpf(x); }
__device__ __forceinline__ float sigm(float x){ return rcp_f(1.f + __expf(-x)); }
__device__ __forceinline__ float tanh_f(float x){ return 1.f - 2.f*rcp_f(__expf(2.f*x) + 1.f); }

// ---- weight repack: frag layout pk[dir][m][CT][ks][lane][8], m={W0,U0,W1,U1}
// element (lane l, slot j) = src[layer][k][col], k = ks*32+(l>>4)*8+j,
// col = CT*16+(l&15). hi at pk[0..524287], lo residual at pk[524288..].
__global__ void __launch_bounds__(256)
repack_w(const float* __restrict__ Wf, const float* __restrict__ Uf,
         const float* __restrict__ Wb, const float* __restrict__ Ub,
         unsigned short* __restrict__ pk)
{
  int flat = blockIdx.x*256 + threadIdx.x;        // 0 .. 524287
  int j  = flat & 7;
  int lx = (flat >> 3)  & 63;
  int ks = (flat >> 9)  & 3;
  int CT = (flat >> 11) & 31;
  int m  = (flat >> 16) & 3;
  int dr = (flat >> 18) & 1;
  int k  = ks*32 + (lx >> 4)*8 + j;
  int cc = CT*16 + (lx & 15);
  const float* src = dr ? ((m & 1) ? Ub : Wb) : ((m & 1) ? Uf : Wf);
  int layer = m >> 1;
  float v = src[((size_t)layer*ND + k)*512 + cc];
  unsigned short hi = f2bf(v);
  pk[flat]            = hi;
  pk[flat + 8*NFRAG]  = f2bf(v - bf2f(hi));   // lo residual (8 elems/frag)
}

__global__ void __launch_bounds__(NTHR, 2)
bilstm_mfma(const float* __restrict__ x,
            const float* __restrict__ bf_, const float* __restrict__ bb_,
            const unsigned short* __restrict__ pk,
            float* __restrict__ out)
{
  // fragment-packed activation buffers: [4 ks][64 lanes][8] ushort = 4KB each
  __shared__ __align__(16) unsigned short xh[2048],  xl[2048];
  __shared__ __align__(16) unsigned short h0h[2][2048], h0l[2][2048];
  __shared__ __align__(16) unsigned short h1h[2][2048], h1l[2][2048];

  const int tid = threadIdx.x;
  const int dir = blockIdx.y;
  const int b0  = blockIdx.x * 16;
  const int w    = tid >> 6;         // wave 0..7
  const int l    = tid & 63;
  const int col  = l & 15;
  const int kg   = l >> 4;           // 0..3
  const int unit = 16*w + col;       // this lane's hidden unit

  const float* Bias = dir ? bb_ : bf_;
  float bia0[4], bia1[4];
  #pragma unroll
  for (int i = 0; i < 4; ++i){
    bia0[i] = Bias[unit + 128*i];
    bia1[i] = Bias[512 + unit + 128*i];
  }

  // zero t=0 read buffers
  for (int i = tid; i < 2048; i += NTHR){
    h0h[0][i] = 0; h0l[0][i] = 0; h1h[0][i] = 0; h1l[0][i] = 0;
  }

  const bf16x8* PK = (const bf16x8*)pk;
  // frag index (bf16x8 units): (((dir*4+m)*32 + CT)*4 + ks)*64 + l ; lo = +NFRAG
  int wb[4][4];                      // [m][i], i -> CT = w + 8i
  #pragma unroll
  for (int m = 0; m < 4; ++m)
    #pragma unroll
    for (int i = 0; i < 4; ++i)
      wb[m][i] = (((dir*4 + m)*32 + (w + 8*i))*4)*64 + l;

  float c0[4] = {0,0,0,0}, c1[4] = {0,0,0,0};

  // x staging map: one float4 per thread, coalesced per row
  const int er = tid >> 5;           // 0..15
  const int ej = (tid & 31) * 4;     // 0..124
  const size_t xbase = ((size_t)(b0 + er)*NTT)*ND + ej;
  const int xidx = ((ej >> 3) << 7) + (er << 3) + (ej & 7);

  __syncthreads();

  for (int t = 0; t < NTT; ++t){
    const int te = dir ? (NTT-1-t) : t;
    const int rb = t & 1, wbf = rb ^ 1;

    // ---- stage x[t] (split hi/lo, fragment-packed)
    {
      float4 v = *(const float4*)(x + xbase + (size_t)te*ND);
      unsigned hh0, hh1, ll0, ll1;
      unsigned short a;
      float f;
      f = v.x; a = f2bf(f); hh0 = a;            ll0 = f2bf(f - bf2f(a));
      f = v.y; a = f2bf(f); hh0 |= (unsigned)a<<16; ll0 |= (unsigned)f2bf(f - bf2f(a))<<16;
      f = v.z; a = f2bf(f); hh1 = a;            ll1 = f2bf(f - bf2f(a));
      f = v.w; a = f2bf(f); hh1 |= (unsigned)a<<16; ll1 |= (unsigned)f2bf(f - bf2f(a))<<16;
      *(uint2*)(xh + xidx) = make_uint2(hh0, hh1);
      *(uint2*)(xl + xidx) = make_uint2(ll0, ll1);
    }
    __syncthreads();   // bar1: x ready; prev-step h writes visible

    f32x4 acc[4];
    float hv[4];

    // ---------- layer 0: z = b0 + x@W0 + h0@U0  (3-term split products)
    #pragma unroll
    for (int i = 0; i < 4; ++i) acc[i] = (f32x4){bia0[i], bia0[i], bia0[i], bia0[i]};
    #pragma unroll
    for (int ks = 0; ks < 4; ++ks){
      bf16x8 a1h = *(const bf16x8*)(xh + ks*512 + l*8);
      bf16x8 a1l = *(const bf16x8*)(xl + ks*512 + l*8);
      bf16x8 a2h = *(const bf16x8*)(h0h[rb] + ks*512 + l*8);
      bf16x8 a2l = *(const bf16x8*)(h0l[rb] + ks*512 + l*8);
      #pragma unroll
      for (int i = 0; i < 4; ++i){
        bf16x8 bwh = PK[wb[0][i] + ks*64];
        bf16x8 bwl = PK[wb[0][i] + ks*64 + NFRAG];
        bf16x8 buh = PK[wb[1][i] + ks*64];
        bf16x8 bul = PK[wb[1][i] + ks*64 + NFRAG];
        acc[i] = __builtin_amdgcn_mfma_f32_16x16x32_bf16(a1h, bwh, acc[i], 0, 0, 0);
        acc[i] = __builtin_amdgcn_mfma_f32_16x16x32_bf16(a1l, bwh, acc[i], 0, 0, 0);
        acc[i] = __builtin_amdgcn_mfma_f32_16x16x32_bf16(a1h, bwl, acc[i], 0, 0, 0);
        acc[i] = __builtin_amdgcn_mfma_f32_16x16x32_bf16(a2h, buh, acc[i], 0, 0, 0);
        acc[i] = __builtin_amdgcn_mfma_f32_16x16x32_bf16(a2l, buh, acc[i], 0, 0, 0);
        acc[i] = __builtin_amdgcn_mfma_f32_16x16x32_bf16(a2h, bul, acc[i], 0, 0, 0);
      }
    }
    #pragma unroll
    for (int q = 0; q < 4; ++q){
      float ig = sigm(acc[0][q]);
      float fg = sigm(acc[1][q]);
      float gg = tanh_f(acc[2][q]);
      float og = sigm(acc[3][q]);
      float cv = __builtin_fmaf(fg, c0[q], ig*gg);
      c0[q] = cv;
      hv[q] = og * tanh_f(cv);
    }
    {
      int base = ((unit >> 3) << 7) + (unit & 7);
      #pragma unroll
      for (int q = 0; q < 4; ++q){
        int row = kg*4 + q;
        unsigned short a = f2bf(hv[q]);
        h0h[wbf][base + row*8] = a;
        h0l[wbf][base + row*8] = f2bf(hv[q] - bf2f(a));
      }
    }
    __syncthreads();   // bar2: new h0 ready

    // ---------- layer 1: z = b1 + h0@W1 + h1@U1
    #pragma unroll
    for (int i = 0; i < 4; ++i) acc[i] = (f32x4){bia1[i], bia1[i], bia1[i], bia1[i]};
    #pragma unroll
    for (int ks = 0; ks < 4; ++ks){
      bf16x8 a1h = *(const bf16x8*)(h0h[wbf] + ks*512 + l*8);
      bf16x8 a1l = *(const bf16x8*)(h0l[wbf] + ks*512 + l*8);
      bf16x8 a2h = *(const bf16x8*)(h1h[rb] + ks*512 + l*8);
      bf16x8 a2l = *(const bf16x8*)(h1l[rb] + ks*512 + l*8);
      #pragma unroll
      for (int i = 0; i < 4; ++i){
        bf16x8 bwh = PK[wb[2][i] + ks*64];
        bf16x8 bwl = PK[wb[2][i] + ks*64 + NFRAG];
        bf16x8 buh = PK[wb[3][i] + ks*64];
        bf16x8 bul = PK[wb[3][i] + ks*64 + NFRAG];
        acc[i] = __builtin_amdgcn_mfma_f32_16x16x32_bf16(a1h, bwh, acc[i], 0, 0, 0);
        acc[i] = __builtin_amdgcn_mfma_f32_16x16x32_bf16(a1l, bwh, acc[i], 0, 0, 0);
        acc[i] = __builtin_amdgcn_mfma_f32_16x16x32_bf16(a1h, bwl, acc[i], 0, 0, 0);
        acc[i] = __builtin_amdgcn_mfma_f32_16x16x32_bf16(a2h, buh, acc[i], 0, 0, 0);
        acc[i] = __builtin_amdgcn_mfma_f32_16x16x32_bf16(a2l, buh, acc[i], 0, 0, 0);
        acc[i] = __builtin_amdgcn_mfma_f32_16x16x32_bf16(a2h, bul, acc[i], 0, 0, 0);
      }
    }
    #pragma unroll
    for (int q = 0; q < 4; ++q){
      float ig = sigm(acc[0][q]);
      float fg = sigm(acc[1][q]);
      float gg = tanh_f(acc[2][q]);
      float og = sigm(acc[3][q]);
      float cv = __builtin_fmaf(fg, c1[q], ig*gg);
      c1[q] = cv;
      hv[q] = og * tanh_f(cv);
    }
    {
      int base = ((unit >> 3) << 7) + (unit & 7);
      #pragma unroll
      for (int q = 0; q < 4; ++q){
        int row = kg*4 + q;
        unsigned short a = f2bf(hv[q]);
        h1h[wbf][base + row*8] = a;
        h1l[wbf][base + row*8] = f2bf(hv[q] - bf2f(a));
        atomicAdd(out + ((size_t)(b0 + row)*NTT + te)*ND + unit, 0.5f*hv[q]);
      }
    }
    // no trailing barrier: bar1/bar2 of t+1 order all buffer reuse
  }
}

extern "C" void kernel_launch(void* const* d_in, const int* in_sizes, int n_in,
                              void* d_out, int out_size, void* d_ws, size_t ws_size,
                              hipStream_t stream)
{
  const float* x  = (const float*)d_in[0];
  const float* Wf = (const float*)d_in[1];
  const float* Uf = (const float*)d_in[2];
  const float* bf = (const float*)d_in[3];
  const float* Wb = (const float*)d_in[4];
  const float* Ub = (const float*)d_in[5];
  const float* bb = (const float*)d_in[6];
  float* out = (float*)d_out;

  unsigned short* pk = (unsigned short*)d_ws;   // 2 MB packed weights (hi+lo)

  repack_w<<<2048, 256, 0, stream>>>(Wf, Uf, Wb, Ub, pk);
  hipMemsetAsync(out, 0, (size_t)out_size*sizeof(float), stream);
  dim3 grid(NB/16, 2), blk(NTHR);
  bilstm_mfma<<<grid, blk, 0, stream>>>(x, bf, bb, pk, out);
}

// Round 5
// 2046.056 us; speedup vs baseline: 11.5102x; 3.4930x over previous
//
#include <hip/hip_runtime.h>

// BiLSTM: B=2048, T=200, D=U=128, 2 layers, bidirectional, merge='ave'.
// R4: CU-resident weights. fp16 single-precision weights (rel 2^-12),
// hi/lo-split fp16 activations (2-term MFMA). Per (batch16, dir) block:
//   W0,U0 -> 128 resident VGPRs/lane; W1 -> 128KB LDS (staged once);
//   U1    -> streamed 128KB/block/step (L2-hot), prefetched in 2 halves.
// LDS 160KB exactly: W1 128K + h0 dbuf split 16K + h1 single split 8K
// (defer-write after next bar1) + x split 8K. AITER-proven config
// (8 waves x 256 VGPR x 160KB LDS).

#define NB   2048
#define NTT  200
#define ND   128
#define NTHR 512   // 8 waves

typedef _Float16 f16x8 __attribute__((ext_vector_type(8)));
typedef _Float16 f16x4 __attribute__((ext_vector_type(4)));
typedef float    f32x4 __attribute__((ext_vector_type(4)));

__device__ __forceinline__ float rcp_f(float x){ return __builtin_amdgcn_rcpf(x); }
__device__ __forceinline__ float sigm(float x){ return rcp_f(1.f + __expf(-x)); }
__device__ __forceinline__ float tanh_f(float x){ return 1.f - 2.f*rcp_f(__expf(2.f*x) + 1.f); }

// ---- weight repack to fp16 frags: pk[dir][m][CT][ks][lane][8], m={W0,U0,W1,U1}
// element (lane l, slot j) = src[layer][k][col], k=ks*32+(l>>4)*8+j, col=CT*16+(l&15)
__global__ void __launch_bounds__(256)
repack_w(const float* __restrict__ Wf, const float* __restrict__ Uf,
         const float* __restrict__ Wb, const float* __restrict__ Ub,
         _Float16* __restrict__ pk)
{
  int flat = blockIdx.x*256 + threadIdx.x;        // 0 .. 524287
  int j  = flat & 7;
  int lx = (flat >> 3)  & 63;
  int ks = (flat >> 9)  & 3;
  int CT = (flat >> 11) & 31;
  int m  = (flat >> 16) & 3;
  int dr = (flat >> 18) & 1;
  int k  = ks*32 + (lx >> 4)*8 + j;
  int cc = CT*16 + (lx & 15);
  const float* src = dr ? ((m & 1) ? Ub : Wb) : ((m & 1) ? Uf : Wf);
  int layer = m >> 1;
  pk[flat] = (_Float16)src[((size_t)layer*ND + k)*512 + cc];
}

__global__ void __launch_bounds__(NTHR, 2)
bilstm_mfma(const float* __restrict__ x,
            const float* __restrict__ bf_, const float* __restrict__ bb_,
            const _Float16* __restrict__ pk,
            float* __restrict__ out)
{
  extern __shared__ char smem_raw[];
  _Float16* S   = (_Float16*)smem_raw;
  _Float16* w1s = S;                 // 65536 halves (128KB)
  _Float16* h0h = S + 65536;         // 2 bufs x 2048
  _Float16* h0l = S + 65536 + 4096;  // 2 bufs x 2048
  _Float16* h1h = S + 65536 + 8192;  // 2048 (single buf)
  _Float16* h1l = S + 65536 + 10240; // 2048
  _Float16* xh  = S + 65536 + 12288; // 2048
  _Float16* xl  = S + 65536 + 14336; // 2048  -> total 81920 halves = 160KB

  const int tid = threadIdx.x;
  const int dir = blockIdx.y;
  const int b0  = blockIdx.x * 16;
  const int w    = tid >> 6;         // wave 0..7
  const int l    = tid & 63;
  const int col  = l & 15;
  const int kg   = l >> 4;           // 0..3
  const int unit = 16*w + col;

  const f16x8* PKH = (const f16x8*)pk;

  // ---- stage W1 into LDS (once)
  {
    const f16x8* w1g = PKH + (size_t)(dir*4 + 2)*32*4*64;
    f16x8* w1d = (f16x8*)w1s;
    for (int idx = tid; idx < 8192; idx += NTHR) w1d[idx] = w1g[idx];
  }

  // ---- resident W0,U0 fragments (128 VGPRs/lane)
  f16x8 w0r[4][4], u0r[4][4];        // [i][ks]
  #pragma unroll
  for (int i = 0; i < 4; ++i)
    #pragma unroll
    for (int ks = 0; ks < 4; ++ks){
      w0r[i][ks] = PKH[(size_t)(((dir*4 + 0)*32 + (w + 8*i))*4 + ks)*64 + l];
      u0r[i][ks] = PKH[(size_t)(((dir*4 + 1)*32 + (w + 8*i))*4 + ks)*64 + l];
    }

  const float* Bias = dir ? bb_ : bf_;
  float bia0[4], bia1[4];
  #pragma unroll
  for (int i = 0; i < 4; ++i){
    bia0[i] = Bias[unit + 128*i];
    bia1[i] = Bias[512 + unit + 128*i];
  }

  // zero initial h state
  for (int i = tid; i < 4096; i += NTHR){ h0h[i] = (_Float16)0.f; h0l[i] = (_Float16)0.f; }
  for (int i = tid; i < 2048; i += NTHR){ h1h[i] = (_Float16)0.f; h1l[i] = (_Float16)0.f; }

  float c0[4] = {0,0,0,0}, c1[4] = {0,0,0,0};
  float hvd[4] = {0,0,0,0};          // deferred h1 value (t-1)

  const int er = tid >> 5;           // 0..15
  const int ej = (tid & 31) * 4;     // 0..124
  const size_t xbase = ((size_t)(b0 + er)*NTT)*ND + ej;
  const int xidx = ((ej >> 3) << 7) + (er << 3) + (ej & 7);
  const int hbase = ((unit >> 3) << 7) + (unit & 7);

  __syncthreads();

  for (int t = 0; t < NTT; ++t){
    const int te = dir ? (NTT-1-t) : t;
    const int rb = t & 1, wb = rb ^ 1;

    // prefetch U1 first half (ks=0,1) — consumed after bar2, huge window
    f16x8 u1pA[2][4];
    #pragma unroll
    for (int ks = 0; ks < 2; ++ks)
      #pragma unroll
      for (int i = 0; i < 4; ++i)
        u1pA[ks][i] = PKH[(size_t)(((dir*4 + 3)*32 + (w + 8*i))*4 + ks)*64 + l];

    // stage x[t] split hi/lo (P2 phase: x only read in P1, safe)
    {
      float4 xv = *(const float4*)(x + xbase + (size_t)te*ND);
      float vv[4] = {xv.x, xv.y, xv.z, xv.w};
      f16x4 hx, lo;
      #pragma unroll
      for (int q = 0; q < 4; ++q){
        _Float16 hh = (_Float16)vv[q];
        hx[q] = hh; lo[q] = (_Float16)(vv[q] - (float)hh);
      }
      *(f16x4*)(xh + xidx) = hx;
      *(f16x4*)(xl + xidx) = lo;
    }
    __syncthreads();   // bar1: x/h0[rb]/h1 ready; all P2(t-1) reads done

    // deferred h1 write (value from t-1; zeros at t=0)
    #pragma unroll
    for (int q = 0; q < 4; ++q){
      _Float16 hh = (_Float16)hvd[q];
      h1h[hbase + (kg*4 + q)*8] = hh;
      h1l[hbase + (kg*4 + q)*8] = (_Float16)(hvd[q] - (float)hh);
    }

    f32x4 acc[4];
    float hv[4];

    // ---------- layer 0: z = b0 + x@W0 + h0@U0 (weights in registers)
    #pragma unroll
    for (int i = 0; i < 4; ++i) acc[i] = (f32x4){bia0[i], bia0[i], bia0[i], bia0[i]};
    #pragma unroll
    for (int ks = 0; ks < 4; ++ks){
      f16x8 a1h = *(const f16x8*)(xh + ks*512 + l*8);
      f16x8 a1l = *(const f16x8*)(xl + ks*512 + l*8);
      f16x8 a2h = *(const f16x8*)(h0h + rb*2048 + ks*512 + l*8);
      f16x8 a2l = *(const f16x8*)(h0l + rb*2048 + ks*512 + l*8);
      #pragma unroll
      for (int i = 0; i < 4; ++i){
        acc[i] = __builtin_amdgcn_mfma_f32_16x16x32_f16(a1h, w0r[i][ks], acc[i], 0, 0, 0);
        acc[i] = __builtin_amdgcn_mfma_f32_16x16x32_f16(a1l, w0r[i][ks], acc[i], 0, 0, 0);
        acc[i] = __builtin_amdgcn_mfma_f32_16x16x32_f16(a2h, u0r[i][ks], acc[i], 0, 0, 0);
        acc[i] = __builtin_amdgcn_mfma_f32_16x16x32_f16(a2l, u0r[i][ks], acc[i], 0, 0, 0);
      }
    }
    #pragma unroll
    for (int q = 0; q < 4; ++q){
      float ig = sigm(acc[0][q]);
      float fg = sigm(acc[1][q]);
      float gg = tanh_f(acc[2][q]);
      float og = sigm(acc[3][q]);
      float cv = __builtin_fmaf(fg, c0[q], ig*gg);
      c0[q] = cv;
      hv[q] = og * tanh_f(cv);
    }
    #pragma unroll
    for (int q = 0; q < 4; ++q){
      _Float16 hh = (_Float16)hv[q];
      h0h[wb*2048 + hbase + (kg*4 + q)*8] = hh;
      h0l[wb*2048 + hbase + (kg*4 + q)*8] = (_Float16)(hv[q] - (float)hh);
    }
    __syncthreads();   // bar2: h0[wb] ready; h1 writes done

    // prefetch U1 second half (ks=2,3) — consumed ~2 ks-groups later
    f16x8 u1pB[2][4];
    #pragma unroll
    for (int ks = 0; ks < 2; ++ks)
      #pragma unroll
      for (int i = 0; i < 4; ++i)
        u1pB[ks][i] = PKH[(size_t)(((dir*4 + 3)*32 + (w + 8*i))*4 + (ks+2))*64 + l];

    // ---------- layer 1: z = b1 + h0@W1 + h1@U1 (W1 from LDS, U1 prefetched)
    #pragma unroll
    for (int i = 0; i < 4; ++i) acc[i] = (f32x4){bia1[i], bia1[i], bia1[i], bia1[i]};
    const f16x8* w1d = (const f16x8*)w1s;
    #pragma unroll
    for (int ks = 0; ks < 4; ++ks){
      f16x8 a1h = *(const f16x8*)(h0h + wb*2048 + ks*512 + l*8);
      f16x8 a1l = *(const f16x8*)(h0l + wb*2048 + ks*512 + l*8);
      f16x8 a2h = *(const f16x8*)(h1h + ks*512 + l*8);
      f16x8 a2l = *(const f16x8*)(h1l + ks*512 + l*8);
      #pragma unroll
      for (int i = 0; i < 4; ++i){
        f16x8 bw1 = w1d[(size_t)((w + 8*i)*4 + ks)*64 + l];
        f16x8 bu1 = (ks < 2) ? u1pA[ks][i] : u1pB[ks-2][i];
        acc[i] = __builtin_amdgcn_mfma_f32_16x16x32_f16(a1h, bw1, acc[i], 0, 0, 0);
        acc[i] = __builtin_amdgcn_mfma_f32_16x16x32_f16(a1l, bw1, acc[i], 0, 0, 0);
        acc[i] = __builtin_amdgcn_mfma_f32_16x16x32_f16(a2h, bu1, acc[i], 0, 0, 0);
        acc[i] = __builtin_amdgcn_mfma_f32_16x16x32_f16(a2l, bu1, acc[i], 0, 0, 0);
      }
    }
    #pragma unroll
    for (int q = 0; q < 4; ++q){
      float ig = sigm(acc[0][q]);
      float fg = sigm(acc[1][q]);
      float gg = tanh_f(acc[2][q]);
      float og = sigm(acc[3][q]);
      float cv = __builtin_fmaf(fg, c1[q], ig*gg);
      c1[q] = cv;
      float hh = og * tanh_f(cv);
      hvd[q] = hh;      // deferred LDS write at next bar1
      atomicAdd(out + ((size_t)(b0 + kg*4 + q)*NTT + te)*ND + unit, 0.5f*hh);
    }
    // no trailing barrier: next-iter bar1/bar2 order all reuse
  }
}

extern "C" void kernel_launch(void* const* d_in, const int* in_sizes, int n_in,
                              void* d_out, int out_size, void* d_ws, size_t ws_size,
                              hipStream_t stream)
{
  const float* x  = (const float*)d_in[0];
  const float* Wf = (const float*)d_in[1];
  const float* Uf = (const float*)d_in[2];
  const float* bf = (const float*)d_in[3];
  const float* Wb = (const float*)d_in[4];
  const float* Ub = (const float*)d_in[5];
  const float* bb = (const float*)d_in[6];
  float* out = (float*)d_out;

  _Float16* pk = (_Float16*)d_ws;   // 1 MB packed fp16 weights

  (void)hipFuncSetAttribute((const void*)bilstm_mfma,
                            hipFuncAttributeMaxDynamicSharedMemorySize, 163840);

  repack_w<<<2048, 256, 0, stream>>>(Wf, Uf, Wb, Ub, pk);
  hipMemsetAsync(out, 0, (size_t)out_size*sizeof(float), stream);
  dim3 grid(NB/16, 2), blk(NTHR);
  bilstm_mfma<<<grid, blk, 163840, stream>>>(x, bf, bb, pk, out);
}

// Round 6
// 1215.192 us; speedup vs baseline: 19.3800x; 1.6837x over previous
//
#include <hip/hip_runtime.h>

// BiLSTM: B=2048, T=200, D=U=128, 2 layers, bidirectional, merge='ave'.
// R5: pure-fp16 weights AND activations (single term per product; R2's bf16
// measured 2.15e-2 -> fp16 is 8x finer => ~3-8e-3, under 1.86e-2 threshold).
//  - W0,U0 resident in VGPRs; W1 in LDS (staged once); U1 streamed from L2
//    (issued at step top, consumed after bar2).
//  - raw barriers (lgkmcnt-only drain): global loads/atomics span barriers.
//  - x pipelined across steps: load(t+1) issued at step top, LDS-written at
//    step end into a double buffer -> HBM latency off the critical path.
// LDS: W1 128K + h0 dbuf 8K + h1 4K + x dbuf 8K = 148KB.

#define NB   2048
#define NTT  200
#define ND   128
#define NTHR 512   // 8 waves

typedef _Float16 f16x8 __attribute__((ext_vector_type(8)));
typedef _Float16 f16x4 __attribute__((ext_vector_type(4)));
typedef float    f32x4 __attribute__((ext_vector_type(4)));

#define BARRIER() asm volatile("s_waitcnt lgkmcnt(0)\n\ts_barrier" ::: "memory")

__device__ __forceinline__ float rcp_f(float x){ return __builtin_amdgcn_rcpf(x); }
__device__ __forceinline__ float sigm(float x){ return rcp_f(1.f + __expf(-x)); }
__device__ __forceinline__ float tanh_f(float x){ return 1.f - 2.f*rcp_f(__expf(2.f*x) + 1.f); }

// ---- weight repack to fp16 frags: pk[dir][m][CT][ks][lane][8], m={W0,U0,W1,U1}
// element (lane l, slot j) = src[layer][k][col], k=ks*32+(l>>4)*8+j, col=CT*16+(l&15)
__global__ void __launch_bounds__(256)
repack_w(const float* __restrict__ Wf, const float* __restrict__ Uf,
         const float* __restrict__ Wb, const float* __restrict__ Ub,
         _Float16* __restrict__ pk)
{
  int flat = blockIdx.x*256 + threadIdx.x;        // 0 .. 524287
  int j  = flat & 7;
  int lx = (flat >> 3)  & 63;
  int ks = (flat >> 9)  & 3;
  int CT = (flat >> 11) & 31;
  int m  = (flat >> 16) & 3;
  int dr = (flat >> 18) & 1;
  int k  = ks*32 + (lx >> 4)*8 + j;
  int cc = CT*16 + (lx & 15);
  const float* src = dr ? ((m & 1) ? Ub : Wb) : ((m & 1) ? Uf : Wf);
  int layer = m >> 1;
  pk[flat] = (_Float16)src[((size_t)layer*ND + k)*512 + cc];
}

__global__ void __launch_bounds__(NTHR, 2)
bilstm_mfma(const float* __restrict__ x,
            const float* __restrict__ bf_, const float* __restrict__ bb_,
            const _Float16* __restrict__ pk,
            float* __restrict__ out)
{
  extern __shared__ char smem_raw[];
  _Float16* w1s = (_Float16*)smem_raw;   // 65536 halves (128KB)
  _Float16* h0a = w1s + 65536;           // 2 bufs x 2048 (8KB)
  _Float16* h1a = h0a + 4096;            // 2048 (4KB)
  _Float16* xb  = h1a + 2048;            // 2 bufs x 2048 (8KB)  total 151552B

  const int tid = threadIdx.x;
  const int dir = blockIdx.y;
  const int b0  = blockIdx.x * 16;
  const int w    = tid >> 6;         // wave 0..7
  const int l    = tid & 63;
  const int col  = l & 15;
  const int kg   = l >> 4;           // 0..3
  const int unit = 16*w + col;

  const f16x8* PKH = (const f16x8*)pk;

  // ---- stage W1 into LDS (once)
  {
    const f16x8* w1g = PKH + (size_t)(dir*4 + 2)*32*4*64;
    f16x8* w1d = (f16x8*)w1s;
    for (int idx = tid; idx < 8192; idx += NTHR) w1d[idx] = w1g[idx];
  }

  // ---- resident W0,U0 fragments (128 VGPRs/lane)
  f16x8 w0r[4][4], u0r[4][4];        // [i][ks]
  #pragma unroll
  for (int i = 0; i < 4; ++i)
    #pragma unroll
    for (int ks = 0; ks < 4; ++ks){
      w0r[i][ks] = PKH[(size_t)(((dir*4 + 0)*32 + (w + 8*i))*4 + ks)*64 + l];
      u0r[i][ks] = PKH[(size_t)(((dir*4 + 1)*32 + (w + 8*i))*4 + ks)*64 + l];
    }

  const float* Bias = dir ? bb_ : bf_;
  float bia0[4], bia1[4];
  #pragma unroll
  for (int i = 0; i < 4; ++i){
    bia0[i] = Bias[unit + 128*i];
    bia1[i] = Bias[512 + unit + 128*i];
  }

  // zero initial h state
  for (int i = tid; i < 4096; i += NTHR) h0a[i] = (_Float16)0.f;
  for (int i = tid; i < 2048; i += NTHR) h1a[i] = (_Float16)0.f;

  const int er = tid >> 5;           // 0..15
  const int ej = (tid & 31) * 4;     // 0..124
  const size_t xbase = ((size_t)(b0 + er)*NTT)*ND + ej;
  const int xidx = ((ej >> 3) << 7) + (er << 3) + (ej & 7);
  const int hbase = ((unit >> 3) << 7) + (unit & 7);

  // prologue: stage x(t=0) into xb[0]
  {
    const int te0 = dir ? (NTT-1) : 0;
    float4 xv = *(const float4*)(x + xbase + (size_t)te0*ND);
    float vv[4] = {xv.x, xv.y, xv.z, xv.w};
    f16x4 hx;
    #pragma unroll
    for (int q = 0; q < 4; ++q) hx[q] = (_Float16)vv[q];
    *(f16x4*)(xb + xidx) = hx;
  }

  float c0[4] = {0,0,0,0}, c1[4] = {0,0,0,0};
  float hvd[4] = {0,0,0,0};          // deferred h1 value (t-1)

  __syncthreads();

  for (int t = 0; t < NTT; ++t){
    const int te = dir ? (NTT-1-t) : t;
    const int rb = t & 1, wb = rb ^ 1;

    // deferred h1(t-1) write (zeros at t=0; visible at bar2)
    #pragma unroll
    for (int q = 0; q < 4; ++q)
      h1a[hbase + (kg*4 + q)*8] = (_Float16)hvd[q];

    // issue U1(t) loads (consumed after bar2 -> full L0 phase of cover)
    f16x8 u1p[4][4];
    #pragma unroll
    for (int ks = 0; ks < 4; ++ks)
      #pragma unroll
      for (int i = 0; i < 4; ++i)
        u1p[ks][i] = PKH[(size_t)(((dir*4 + 3)*32 + (w + 8*i))*4 + ks)*64 + l];

    // issue x(t+1) load (converted + LDS-written at step end)
    const int tn = (t + 1 < NTT) ? (t + 1) : t;
    const int ten = dir ? (NTT-1-tn) : tn;
    float4 xv = *(const float4*)(x + xbase + (size_t)ten*ND);

    f32x4 acc[4];
    float hv[4];

    // ---------- layer 0: z = b0 + x@W0 + h0@U0 (weights in registers)
    #pragma unroll
    for (int i = 0; i < 4; ++i) acc[i] = (f32x4){bia0[i], bia0[i], bia0[i], bia0[i]};
    #pragma unroll
    for (int ks = 0; ks < 4; ++ks){
      f16x8 a1 = *(const f16x8*)(xb  + rb*2048 + ks*512 + l*8);
      f16x8 a2 = *(const f16x8*)(h0a + rb*2048 + ks*512 + l*8);
      #pragma unroll
      for (int i = 0; i < 4; ++i){
        acc[i] = __builtin_amdgcn_mfma_f32_16x16x32_f16(a1, w0r[i][ks], acc[i], 0, 0, 0);
        acc[i] = __builtin_amdgcn_mfma_f32_16x16x32_f16(a2, u0r[i][ks], acc[i], 0, 0, 0);
      }
    }
    #pragma unroll
    for (int q = 0; q < 4; ++q){
      float ig = sigm(acc[0][q]);
      float fg = sigm(acc[1][q]);
      float gg = tanh_f(acc[2][q]);
      float og = sigm(acc[3][q]);
      float cv = __builtin_fmaf(fg, c0[q], ig*gg);
      c0[q] = cv;
      hv[q] = og * tanh_f(cv);
    }
    #pragma unroll
    for (int q = 0; q < 4; ++q)
      h0a[wb*2048 + hbase + (kg*4 + q)*8] = (_Float16)hv[q];

    BARRIER();   // bar2: h0[wb] + h1 ready (lgkm drain only)

    // ---------- layer 1: z = b1 + h0@W1 + h1@U1 (W1 LDS, U1 prefetched)
    #pragma unroll
    for (int i = 0; i < 4; ++i) acc[i] = (f32x4){bia1[i], bia1[i], bia1[i], bia1[i]};
    const f16x8* w1d = (const f16x8*)w1s;
    #pragma unroll
    for (int ks = 0; ks < 4; ++ks){
      f16x8 a1 = *(const f16x8*)(h0a + wb*2048 + ks*512 + l*8);
      f16x8 a2 = *(const f16x8*)(h1a + ks*512 + l*8);
      #pragma unroll
      for (int i = 0; i < 4; ++i){
        f16x8 bw1 = w1d[(size_t)((w + 8*i)*4 + ks)*64 + l];
        acc[i] = __builtin_amdgcn_mfma_f32_16x16x32_f16(a1, bw1,        acc[i], 0, 0, 0);
        acc[i] = __builtin_amdgcn_mfma_f32_16x16x32_f16(a2, u1p[ks][i], acc[i], 0, 0, 0);
      }
    }
    #pragma unroll
    for (int q = 0; q < 4; ++q){
      float ig = sigm(acc[0][q]);
      float fg = sigm(acc[1][q]);
      float gg = tanh_f(acc[2][q]);
      float og = sigm(acc[3][q]);
      float cv = __builtin_fmaf(fg, c1[q], ig*gg);
      c1[q] = cv;
      float hh = og * tanh_f(cv);
      hvd[q] = hh;      // LDS-written after next barrier
      atomicAdd(out + ((size_t)(b0 + kg*4 + q)*NTT + te)*ND + unit, 0.5f*hh);
    }

    // convert + stage x(t+1) into xb[wb] (WAR safe: that buffer's readers
    // finished in L0(t-1), separated by two barriers)
    {
      float vv[4] = {xv.x, xv.y, xv.z, xv.w};
      f16x4 hx;
      #pragma unroll
      for (int q = 0; q < 4; ++q) hx[q] = (_Float16)vv[q];
      *(f16x4*)(xb + wb*2048 + xidx) = hx;
    }

    BARRIER();   // barEnd (= bar1 of t+1): xb[wb] ready; h1-WAR ordered
  }
}

extern "C" void kernel_launch(void* const* d_in, const int* in_sizes, int n_in,
                              void* d_out, int out_size, void* d_ws, size_t ws_size,
                              hipStream_t stream)
{
  const float* x  = (const float*)d_in[0];
  const float* Wf = (const float*)d_in[1];
  const float* Uf = (const float*)d_in[2];
  const float* bf = (const float*)d_in[3];
  const float* Wb = (const float*)d_in[4];
  const float* Ub = (const float*)d_in[5];
  const float* bb = (const float*)d_in[6];
  float* out = (float*)d_out;

  _Float16* pk = (_Float16*)d_ws;   // 1 MB packed fp16 weights

  (void)hipFuncSetAttribute((const void*)bilstm_mfma,
                            hipFuncAttributeMaxDynamicSharedMemorySize, 151552);

  repack_w<<<2048, 256, 0, stream>>>(Wf, Uf, Wb, Ub, pk);
  hipMemsetAsync(out, 0, (size_t)out_size*sizeof(float), stream);
  dim3 grid(NB/16, 2), blk(NTHR);
  bilstm_mfma<<<grid, blk, 151552, stream>>>(x, bf, bb, pk, out);
}

// Round 7
// 1033.419 us; speedup vs baseline: 22.7889x; 1.1759x over previous
//
#include <hip/hip_runtime.h>

// BiLSTM: B=2048, T=200, D=U=128, 2 layers, bidirectional, merge='ave'.
// R6: NO per-step global weight stream (R5's 128KB/step U1 L2-stream matched
// the 6.4us step time at the ~20GB/s/CU load wall). Placement:
//   W0,U0,W1 -> register-resident (192 VGPRs/lane of fp16 frags)
//   U1       -> LDS-resident (staged once, 128KB)
// Main loop global ops: 1 x load/step (pipelined) + 4 atomics (deferred-safe).
// LDS: U1 128K + h0 dbuf 8K + h1 4K + x dbuf 8K = 148KB. Raw lgkm barriers.

#define NB   2048
#define NTT  200
#define ND   128
#define NTHR 512   // 8 waves

typedef _Float16 f16x8 __attribute__((ext_vector_type(8)));
typedef _Float16 f16x4 __attribute__((ext_vector_type(4)));
typedef float    f32x4 __attribute__((ext_vector_type(4)));

#define BARRIER() asm volatile("s_waitcnt lgkmcnt(0)\n\ts_barrier" ::: "memory")

__device__ __forceinline__ float rcp_f(float x){ return __builtin_amdgcn_rcpf(x); }
__device__ __forceinline__ float sigm(float x){ return rcp_f(1.f + __expf(-x)); }
__device__ __forceinline__ float tanh_f(float x){ return 1.f - 2.f*rcp_f(__expf(2.f*x) + 1.f); }

// ---- weight repack to fp16 frags: pk[dir][m][CT][ks][lane][8], m={W0,U0,W1,U1}
// element (lane l, slot j) = src[layer][k][col], k=ks*32+(l>>4)*8+j, col=CT*16+(l&15)
__global__ void __launch_bounds__(256)
repack_w(const float* __restrict__ Wf, const float* __restrict__ Uf,
         const float* __restrict__ Wb, const float* __restrict__ Ub,
         _Float16* __restrict__ pk)
{
  int flat = blockIdx.x*256 + threadIdx.x;        // 0 .. 524287
  int j  = flat & 7;
  int lx = (flat >> 3)  & 63;
  int ks = (flat >> 9)  & 3;
  int CT = (flat >> 11) & 31;
  int m  = (flat >> 16) & 3;
  int dr = (flat >> 18) & 1;
  int k  = ks*32 + (lx >> 4)*8 + j;
  int cc = CT*16 + (lx & 15);
  const float* src = dr ? ((m & 1) ? Ub : Wb) : ((m & 1) ? Uf : Wf);
  int layer = m >> 1;
  pk[flat] = (_Float16)src[((size_t)layer*ND + k)*512 + cc];
}

__global__ void __launch_bounds__(NTHR, 2)
bilstm_mfma(const float* __restrict__ x,
            const float* __restrict__ bf_, const float* __restrict__ bb_,
            const _Float16* __restrict__ pk,
            float* __restrict__ out)
{
  extern __shared__ char smem_raw[];
  _Float16* u1s = (_Float16*)smem_raw;   // 65536 halves (128KB)
  _Float16* h0a = u1s + 65536;           // 2 bufs x 2048 (8KB)
  _Float16* h1a = h0a + 4096;            // 2048 (4KB)
  _Float16* xb  = h1a + 2048;            // 2 bufs x 2048 (8KB)  total 151552B

  const int tid = threadIdx.x;
  const int dir = blockIdx.y;
  const int b0  = blockIdx.x * 16;
  const int w    = tid >> 6;         // wave 0..7
  const int l    = tid & 63;
  const int col  = l & 15;
  const int kg   = l >> 4;           // 0..3
  const int unit = 16*w + col;

  const f16x8* PKH = (const f16x8*)pk;

  // ---- stage U1 into LDS (once; read-only afterwards, no barrier needed
  //      for steady-state reads)
  {
    const f16x8* u1g = PKH + (size_t)(dir*4 + 3)*32*4*64;
    f16x8* u1d = (f16x8*)u1s;
    for (int idx = tid; idx < 8192; idx += NTHR) u1d[idx] = u1g[idx];
  }

  // ---- resident W0,U0,W1 fragments (192 VGPRs/lane)
  f16x8 w0r[4][4], u0r[4][4], w1r[4][4];   // [i][ks]
  #pragma unroll
  for (int i = 0; i < 4; ++i)
    #pragma unroll
    for (int ks = 0; ks < 4; ++ks){
      w0r[i][ks] = PKH[(size_t)(((dir*4 + 0)*32 + (w + 8*i))*4 + ks)*64 + l];
      u0r[i][ks] = PKH[(size_t)(((dir*4 + 1)*32 + (w + 8*i))*4 + ks)*64 + l];
      w1r[i][ks] = PKH[(size_t)(((dir*4 + 2)*32 + (w + 8*i))*4 + ks)*64 + l];
    }

  const float* Bias = dir ? bb_ : bf_;
  float bia0[4], bia1[4];
  #pragma unroll
  for (int i = 0; i < 4; ++i){
    bia0[i] = Bias[unit + 128*i];
    bia1[i] = Bias[512 + unit + 128*i];
  }

  // zero initial h state
  for (int i = tid; i < 4096; i += NTHR) h0a[i] = (_Float16)0.f;
  for (int i = tid; i < 2048; i += NTHR) h1a[i] = (_Float16)0.f;

  const int er = tid >> 5;           // 0..15
  const int ej = (tid & 31) * 4;     // 0..124
  const size_t xbase = ((size_t)(b0 + er)*NTT)*ND + ej;
  const int xidx = ((ej >> 3) << 7) + (er << 3) + (ej & 7);
  const int hbase = ((unit >> 3) << 7) + (unit & 7);

  // prologue: stage x(t=0) into xb[0]
  {
    const int te0 = dir ? (NTT-1) : 0;
    float4 xv = *(const float4*)(x + xbase + (size_t)te0*ND);
    float vv[4] = {xv.x, xv.y, xv.z, xv.w};
    f16x4 hx;
    #pragma unroll
    for (int q = 0; q < 4; ++q) hx[q] = (_Float16)vv[q];
    *(f16x4*)(xb + xidx) = hx;
  }

  float c0[4] = {0,0,0,0}, c1[4] = {0,0,0,0};
  float hvd[4] = {0,0,0,0};          // deferred h1 value (t-1)

  __syncthreads();

  for (int t = 0; t < NTT; ++t){
    const int te = dir ? (NTT-1-t) : t;
    const int rb = t & 1, wb = rb ^ 1;

    // issue x(t+1) load FIRST (oldest vm op; converted + LDS-written at
    // step end -> its wait never drains this step's atomics)
    const int tn = (t + 1 < NTT) ? (t + 1) : t;
    const int ten = dir ? (NTT-1-tn) : tn;
    float4 xv = *(const float4*)(x + xbase + (size_t)ten*ND);

    // deferred h1(t-1) write (zeros at t=0; visible at bar2)
    #pragma unroll
    for (int q = 0; q < 4; ++q)
      h1a[hbase + (kg*4 + q)*8] = (_Float16)hvd[q];

    f32x4 acc[4];
    float hv[4];

    // ---------- layer 0: z = b0 + x@W0 + h0@U0 (weights in registers)
    #pragma unroll
    for (int i = 0; i < 4; ++i) acc[i] = (f32x4){bia0[i], bia0[i], bia0[i], bia0[i]};
    #pragma unroll
    for (int ks = 0; ks < 4; ++ks){
      f16x8 a1 = *(const f16x8*)(xb  + rb*2048 + ks*512 + l*8);
      f16x8 a2 = *(const f16x8*)(h0a + rb*2048 + ks*512 + l*8);
      #pragma unroll
      for (int i = 0; i < 4; ++i){
        acc[i] = __builtin_amdgcn_mfma_f32_16x16x32_f16(a1, w0r[i][ks], acc[i], 0, 0, 0);
        acc[i] = __builtin_amdgcn_mfma_f32_16x16x32_f16(a2, u0r[i][ks], acc[i], 0, 0, 0);
      }
    }
    #pragma unroll
    for (int q = 0; q < 4; ++q){
      float ig = sigm(acc[0][q]);
      float fg = sigm(acc[1][q]);
      float gg = tanh_f(acc[2][q]);
      float og = sigm(acc[3][q]);
      float cv = __builtin_fmaf(fg, c0[q], ig*gg);
      c0[q] = cv;
      hv[q] = og * tanh_f(cv);
    }
    #pragma unroll
    for (int q = 0; q < 4; ++q)
      h0a[wb*2048 + hbase + (kg*4 + q)*8] = (_Float16)hv[q];

    BARRIER();   // bar2: h0[wb] + h1 ready (lgkm drain only)

    // ---------- layer 1: z = b1 + h0@W1 + h1@U1 (W1 regs, U1 from LDS)
    #pragma unroll
    for (int i = 0; i < 4; ++i) acc[i] = (f32x4){bia1[i], bia1[i], bia1[i], bia1[i]};
    const f16x8* u1d = (const f16x8*)u1s;
    #pragma unroll
    for (int ks = 0; ks < 4; ++ks){
      f16x8 a1 = *(const f16x8*)(h0a + wb*2048 + ks*512 + l*8);
      f16x8 a2 = *(const f16x8*)(h1a + ks*512 + l*8);
      #pragma unroll
      for (int i = 0; i < 4; ++i){
        f16x8 bu1 = u1d[(size_t)((w + 8*i)*4 + ks)*64 + l];
        acc[i] = __builtin_amdgcn_mfma_f32_16x16x32_f16(a1, w1r[i][ks], acc[i], 0, 0, 0);
        acc[i] = __builtin_amdgcn_mfma_f32_16x16x32_f16(a2, bu1,        acc[i], 0, 0, 0);
      }
    }
    #pragma unroll
    for (int q = 0; q < 4; ++q){
      float ig = sigm(acc[0][q]);
      float fg = sigm(acc[1][q]);
      float gg = tanh_f(acc[2][q]);
      float og = sigm(acc[3][q]);
      float cv = __builtin_fmaf(fg, c1[q], ig*gg);
      c1[q] = cv;
      float hh = og * tanh_f(cv);
      hvd[q] = hh;      // LDS-written after next barrier
      atomicAdd(out + ((size_t)(b0 + kg*4 + q)*NTT + te)*ND + unit, 0.5f*hh);
    }

    // convert + stage x(t+1) into xb[wb] (WAR safe: that buffer's readers
    // finished in L0(t-1), separated by two barriers)
    {
      float vv[4] = {xv.x, xv.y, xv.z, xv.w};
      f16x4 hx;
      #pragma unroll
      for (int q = 0; q < 4; ++q) hx[q] = (_Float16)vv[q];
      *(f16x4*)(xb + wb*2048 + xidx) = hx;
    }

    BARRIER();   // barEnd (= bar1 of t+1): xb[wb] ready; h1-WAR ordered
  }
}

extern "C" void kernel_launch(void* const* d_in, const int* in_sizes, int n_in,
                              void* d_out, int out_size, void* d_ws, size_t ws_size,
                              hipStream_t stream)
{
  const float* x  = (const float*)d_in[0];
  const float* Wf = (const float*)d_in[1];
  const float* Uf = (const float*)d_in[2];
  const float* bf = (const float*)d_in[3];
  const float* Wb = (const float*)d_in[4];
  const float* Ub = (const float*)d_in[5];
  const float* bb = (const float*)d_in[6];
  float* out = (float*)d_out;

  _Float16* pk = (_Float16*)d_ws;   // 1 MB packed fp16 weights

  (void)hipFuncSetAttribute((const void*)bilstm_mfma,
                            hipFuncAttributeMaxDynamicSharedMemorySize, 151552);

  repack_w<<<2048, 256, 0, stream>>>(Wf, Uf, Wb, Ub, pk);
  hipMemsetAsync(out, 0, (size_t)out_size*sizeof(float), stream);
  dim3 grid(NB/16, 2), blk(NTHR);
  bilstm_mfma<<<grid, blk, 151552, stream>>>(x, bf, bb, pk, out);
}